// Round 1
// baseline (8240.148 us; speedup 1.0000x reference)
//
#include <hip/hip_runtime.h>
#include <math.h>

#define Dm   1024
#define Hn   16
#define HDm  64
#define Lm   2048
#define Wm   256
#define Im   3280
#define Vm   32000
#define NLAYER 4
#define EPSf 1e-5f

static __device__ __forceinline__ float clamp10k(float x) {
    return fminf(fmaxf(x, -10000.0f), 10000.0f);
}

// ---------------- embedding gather ----------------
__global__ __launch_bounds__(256) void embed_k(const int* __restrict__ tok,
                                               const float* __restrict__ ew,
                                               float* __restrict__ x) {
    int i = blockIdx.x;
    int t = tok[i];
    const float4* src = (const float4*)(ew + (size_t)t * Dm);
    float4* dst = (float4*)(x + (size_t)i * Dm);
    dst[threadIdx.x] = src[threadIdx.x];
}

// ---------------- RMSNorm over D=1024 (one block per row) ----------------
__global__ __launch_bounds__(256) void rmsnorm_row(const float* __restrict__ x,
                                                   const float* __restrict__ w,
                                                   float* __restrict__ out) {
    __shared__ float red[256];
    int row = blockIdx.x, tid = threadIdx.x;
    float4 vx = ((const float4*)(x + (size_t)row * Dm))[tid];
    vx.x = clamp10k(vx.x); vx.y = clamp10k(vx.y);
    vx.z = clamp10k(vx.z); vx.w = clamp10k(vx.w);
    float ss = vx.x * vx.x + vx.y * vx.y + vx.z * vx.z + vx.w * vx.w;
    red[tid] = ss;
    __syncthreads();
    for (int s = 128; s > 0; s >>= 1) {
        if (tid < s) red[tid] += red[tid + s];
        __syncthreads();
    }
    float mean = red[0] * (1.0f / Dm);
    float inv = 1.0f / sqrtf(fmaxf(mean, EPSf) + EPSf);
    float4 vw = ((const float4*)w)[tid];
    float4 o;
    o.x = vx.x * inv * vw.x;
    o.y = vx.y * inv * vw.y;
    o.z = vx.z * inv * vw.z;
    o.w = vx.w * inv * vw.w;
    if (!isfinite(o.x)) o.x = 0.0f;
    if (!isfinite(o.y)) o.y = 0.0f;
    if (!isfinite(o.z)) o.z = 0.0f;
    if (!isfinite(o.w)) o.w = 0.0f;
    ((float4*)(out + (size_t)row * Dm))[tid] = o;
}

// ---------------- per-head RMSNorm over hd=64 (one wave per (pos,head) row, in-place) ---
__global__ __launch_bounds__(64) void rmsnorm_head(float* __restrict__ qk,
                                                   const float* __restrict__ w) {
    int r = blockIdx.x, lane = threadIdx.x;
    size_t idx = (size_t)r * HDm + lane;
    float xv = clamp10k(qk[idx]);
    float ss = xv * xv;
#pragma unroll
    for (int off = 32; off >= 1; off >>= 1) ss += __shfl_xor(ss, off, 64);
    float mean = ss * (1.0f / HDm);
    float inv = 1.0f / sqrtf(fmaxf(mean, EPSf) + EPSf);
    float o = xv * inv * w[lane];
    qk[idx] = isfinite(o) ? o : 0.0f;
}

// ---------------- GEMM: C(MxN) = A(MxK) @ Wt(NxK)^T + bias, optional clamp(+-50) -------
// M multiple of 64, K multiple of 16 (holds for 1024 and 3280); N guarded.
#define BM 64
#define BN 64
#define BK 16
__global__ __launch_bounds__(256) void gemm_bias_act(const float* __restrict__ A,
                                                     const float* __restrict__ Wt,
                                                     const float* __restrict__ bias,
                                                     float* __restrict__ C,
                                                     int M, int N, int K, int act) {
    __shared__ float As[BK][BM];
    __shared__ float Bs[BK][BN];
    int tid = threadIdx.x;
    int tx = tid & 15, ty = tid >> 4;
    int rowBase = blockIdx.y * BM, colBase = blockIdx.x * BN;
    int lrow = tid >> 2;          // 0..63
    int lcol = (tid & 3) * 4;     // 0,4,8,12
    float acc[4][4] = {{0.0f}};

    for (int k0 = 0; k0 < K; k0 += BK) {
        float4 av = *(const float4*)(A + (size_t)(rowBase + lrow) * K + k0 + lcol);
        As[lcol + 0][lrow] = av.x;
        As[lcol + 1][lrow] = av.y;
        As[lcol + 2][lrow] = av.z;
        As[lcol + 3][lrow] = av.w;

        int gc = colBase + lrow;
        float4 bv = make_float4(0.f, 0.f, 0.f, 0.f);
        if (gc < N) bv = *(const float4*)(Wt + (size_t)gc * K + k0 + lcol);
        Bs[lcol + 0][lrow] = bv.x;
        Bs[lcol + 1][lrow] = bv.y;
        Bs[lcol + 2][lrow] = bv.z;
        Bs[lcol + 3][lrow] = bv.w;
        __syncthreads();

#pragma unroll
        for (int kk = 0; kk < BK; ++kk) {
            float4 a = *(const float4*)&As[kk][ty * 4];
            float4 b = *(const float4*)&Bs[kk][tx * 4];
            float a4[4] = {a.x, a.y, a.z, a.w};
            float b4[4] = {b.x, b.y, b.z, b.w};
#pragma unroll
            for (int i2 = 0; i2 < 4; ++i2)
#pragma unroll
                for (int j = 0; j < 4; ++j) acc[i2][j] += a4[i2] * b4[j];
        }
        __syncthreads();
    }

#pragma unroll
    for (int i2 = 0; i2 < 4; ++i2) {
        int r = rowBase + ty * 4 + i2;
#pragma unroll
        for (int j = 0; j < 4; ++j) {
            int c = colBase + tx * 4 + j;
            if (c < N) {
                float val = acc[i2][j] + bias[c];
                if (act == 1) val = fminf(fmaxf(val, -50.0f), 50.0f);
                C[(size_t)r * N + c] = val;
            }
        }
    }
}

// ---------------- sliding-window causal attention, one block per (query, head) ---------
__global__ __launch_bounds__(256) void attn_k(const float* __restrict__ q,
                                              const float* __restrict__ k,
                                              const float* __restrict__ v,
                                              float* __restrict__ out) {
    int i = blockIdx.x, h = blockIdx.y, tid = threadIdx.x;
    __shared__ float qs[HDm];
    __shared__ float p[256];
    __shared__ float red[256];
    int j0 = i - (Wm - 1);
    if (j0 < 0) j0 = 0;
    int nj = i - j0 + 1;   // 1..256

    const float* qrow = q + (size_t)i * Dm + h * HDm;
    if (tid < HDm) qs[tid] = qrow[tid];
    __syncthreads();

    float s = -INFINITY;
    if (tid < nj) {
        const float* krow = k + (size_t)(j0 + tid) * Dm + h * HDm;
        float acc = 0.0f;
#pragma unroll
        for (int d = 0; d < HDm; ++d) acc += qs[d] * krow[d];
        s = acc * 0.125f;  // 64^-0.5
    }

    // block max
    red[tid] = s;
    __syncthreads();
    for (int st = 128; st > 0; st >>= 1) {
        if (tid < st) red[tid] = fmaxf(red[tid], red[tid + st]);
        __syncthreads();
    }
    float m = red[0];
    __syncthreads();

    float e = (tid < nj) ? expf(s - m) : 0.0f;
    red[tid] = e;
    __syncthreads();
    for (int st = 128; st > 0; st >>= 1) {
        if (tid < st) red[tid] += red[tid + st];
        __syncthreads();
    }
    float denom = red[0];
    p[tid] = e / denom;
    __syncthreads();

    if (tid < HDm) {
        float acc = 0.0f;
        const float* vbase = v + (size_t)j0 * Dm + h * HDm + tid;
        for (int t = 0; t < nj; ++t) acc += p[t] * vbase[(size_t)t * Dm];
        if (!isfinite(acc)) acc = 0.0f;
        out[(size_t)i * Dm + h * HDm + tid] = acc;
    }
}

// ---------------- elementwise: x += t ----------------
__global__ __launch_bounds__(256) void add_k(float* __restrict__ x,
                                             const float* __restrict__ t, int n4) {
    int i = blockIdx.x * 256 + threadIdx.x;
    if (i < n4) {
        float4 a = ((const float4*)x)[i];
        float4 b = ((const float4*)t)[i];
        a.x += b.x; a.y += b.y; a.z += b.z; a.w += b.w;
        ((float4*)x)[i] = a;
    }
}

// ---------------- elementwise: z1 = silu(z1) * z3 ----------------
__global__ __launch_bounds__(256) void swiglu_k(float* __restrict__ z1,
                                                const float* __restrict__ z3, int n4) {
    int i = blockIdx.x * 256 + threadIdx.x;
    if (i < n4) {
        float4 a = ((const float4*)z1)[i];
        float4 b = ((const float4*)z3)[i];
        a.x = a.x / (1.0f + expf(-a.x)) * b.x;
        a.y = a.y / (1.0f + expf(-a.y)) * b.y;
        a.z = a.z / (1.0f + expf(-a.z)) * b.z;
        a.w = a.w / (1.0f + expf(-a.w)) * b.w;
        ((float4*)z1)[i] = a;
    }
}

extern "C" void kernel_launch(void* const* d_in, const int* in_sizes, int n_in,
                              void* d_out, int out_size, void* d_ws, size_t ws_size,
                              hipStream_t stream) {
    const int*   tokens  = (const int*)  d_in[0];
    const float* embed_w = (const float*)d_in[1];
    const float* ln1_w   = (const float*)d_in[2];
    const float* ln2_w   = (const float*)d_in[3];
    const float* wq_w    = (const float*)d_in[4];
    const float* wq_b    = (const float*)d_in[5];
    const float* wk_w    = (const float*)d_in[6];
    const float* wk_b    = (const float*)d_in[7];
    const float* wv_w    = (const float*)d_in[8];
    const float* wv_b    = (const float*)d_in[9];
    const float* wo_w    = (const float*)d_in[10];
    const float* wo_b    = (const float*)d_in[11];
    const float* qn_w    = (const float*)d_in[12];
    const float* kn_w    = (const float*)d_in[13];
    const float* w1_w    = (const float*)d_in[14];
    const float* w1_b    = (const float*)d_in[15];
    const float* w2_w    = (const float*)d_in[16];
    const float* w2_b    = (const float*)d_in[17];
    const float* w3_w    = (const float*)d_in[18];
    const float* w3_b    = (const float*)d_in[19];
    const float* lnf_w   = (const float*)d_in[20];
    const float* lm_w    = (const float*)d_in[21];
    const float* lm_b    = (const float*)d_in[22];
    float* out = (float*)d_out;

    const size_t LD = (size_t)Lm * Dm;   // 2,097,152 floats
    const size_t LI = (size_t)Lm * Im;   // 6,717,440 floats
    float* ws = (float*)d_ws;
    float* x   = ws;          // residual stream
    float* xn  = x   + LD;    // normed activations
    float* qb  = xn  + LD;
    float* kb  = qb  + LD;
    float* vb  = kb  + LD;
    float* att = vb  + LD;    // attention output (pre-Wo)
    float* t2  = att + LD;    // proj / FFN-down output
    float* z1  = t2  + LD;
    float* z3  = z1  + LI;    // total ~28.1M floats = ~112.5 MB

    dim3 gD((Dm + 63) / 64, Lm / 64);   // (16, 32)
    dim3 gI((Im + 63) / 64, Lm / 64);   // (52, 32)
    dim3 gV((Vm + 63) / 64, Lm / 64);   // (500, 32)
    int nLD4 = (int)(LD / 4);
    int nLI4 = (int)(LI / 4);

    embed_k<<<Lm, 256, 0, stream>>>(tokens, embed_w, x);

    for (int l = 0; l < NLAYER; ++l) {
        size_t oDD = (size_t)l * Dm * Dm, oD = (size_t)l * Dm;
        size_t oID = (size_t)l * Im * Dm, oI = (size_t)l * Im;
        size_t oH = (size_t)l * HDm;

        rmsnorm_row<<<Lm, 256, 0, stream>>>(x, ln1_w + oD, xn);
        gemm_bias_act<<<gD, 256, 0, stream>>>(xn, wq_w + oDD, wq_b + oD, qb, Lm, Dm, Dm, 0);
        gemm_bias_act<<<gD, 256, 0, stream>>>(xn, wk_w + oDD, wk_b + oD, kb, Lm, Dm, Dm, 0);
        gemm_bias_act<<<gD, 256, 0, stream>>>(xn, wv_w + oDD, wv_b + oD, vb, Lm, Dm, Dm, 0);
        rmsnorm_head<<<Lm * Hn, 64, 0, stream>>>(qb, qn_w + oH);
        rmsnorm_head<<<Lm * Hn, 64, 0, stream>>>(kb, kn_w + oH);
        attn_k<<<dim3(Lm, Hn), 256, 0, stream>>>(qb, kb, vb, att);
        gemm_bias_act<<<gD, 256, 0, stream>>>(att, wo_w + oDD, wo_b + oD, t2, Lm, Dm, Dm, 0);
        add_k<<<(nLD4 + 255) / 256, 256, 0, stream>>>(x, t2, nLD4);

        rmsnorm_row<<<Lm, 256, 0, stream>>>(x, ln2_w + oD, xn);
        gemm_bias_act<<<gI, 256, 0, stream>>>(xn, w1_w + oID, w1_b + oI, z1, Lm, Im, Dm, 0);
        gemm_bias_act<<<gI, 256, 0, stream>>>(xn, w3_w + oID, w3_b + oI, z3, Lm, Im, Dm, 0);
        swiglu_k<<<(nLI4 + 255) / 256, 256, 0, stream>>>(z1, z3, nLI4);
        gemm_bias_act<<<gD, 256, 0, stream>>>(z1, w2_w + oID, w2_b + oD, t2, Lm, Dm, Im, 0);
        add_k<<<(nLD4 + 255) / 256, 256, 0, stream>>>(x, t2, nLD4);
    }

    rmsnorm_row<<<Lm, 256, 0, stream>>>(x, lnf_w, xn);
    gemm_bias_act<<<gV, 256, 0, stream>>>(xn, lm_w, lm_b, out, Lm, Vm, Dm, 1);
}

// Round 2
// 3491.670 us; speedup vs baseline: 2.3599x; 2.3599x over previous
//
#include <hip/hip_runtime.h>
#include <hip/hip_bf16.h>
#include <math.h>

#define Dm   1024
#define Hn   16
#define HDm  64
#define Lm   2048
#define Wm   256
#define Im   3280
#define Vm   32000
#define NLAYER 4
#define EPSf 1e-5f

typedef unsigned short ushort;
typedef __attribute__((ext_vector_type(8))) short bf16x8;
typedef __attribute__((ext_vector_type(4))) float f32x4;

static __device__ __forceinline__ float clamp10k(float x) {
    return fminf(fmaxf(x, -10000.0f), 10000.0f);
}

static __device__ __forceinline__ ushort f2bf(float f) {
    __hip_bfloat16 h = __float2bfloat16(f);
    return *reinterpret_cast<ushort*>(&h);
}

// async global->LDS, 16 bytes per lane; LDS dest = wave-uniform base + lane*16
static __device__ __forceinline__ void gload16(const ushort* g, ushort* l) {
    __builtin_amdgcn_global_load_lds(
        (const __attribute__((address_space(1))) void*)(const void*)g,
        (__attribute__((address_space(3))) void*)(void*)l, 16, 0, 0);
}

// ---------------- embedding gather ----------------
__global__ __launch_bounds__(256) void embed_k(const int* __restrict__ tok,
                                               const float* __restrict__ ew,
                                               float* __restrict__ x) {
    int i = blockIdx.x;
    int t = tok[i];
    const float4* src = (const float4*)(ew + (size_t)t * Dm);
    float4* dst = (float4*)(x + (size_t)i * Dm);
    dst[threadIdx.x] = src[threadIdx.x];
}

// ---------------- RMSNorm over D=1024, bf16 output ----------------
__global__ __launch_bounds__(256) void rmsnorm_row(const float* __restrict__ x,
                                                   const float* __restrict__ w,
                                                   ushort* __restrict__ out) {
    __shared__ float red[256];
    int row = blockIdx.x, tid = threadIdx.x;
    float4 vx = ((const float4*)(x + (size_t)row * Dm))[tid];
    vx.x = clamp10k(vx.x); vx.y = clamp10k(vx.y);
    vx.z = clamp10k(vx.z); vx.w = clamp10k(vx.w);
    float ss = vx.x * vx.x + vx.y * vx.y + vx.z * vx.z + vx.w * vx.w;
    red[tid] = ss;
    __syncthreads();
    for (int s = 128; s > 0; s >>= 1) {
        if (tid < s) red[tid] += red[tid + s];
        __syncthreads();
    }
    float mean = red[0] * (1.0f / Dm);
    float inv = 1.0f / sqrtf(fmaxf(mean, EPSf) + EPSf);
    float4 vw = ((const float4*)w)[tid];
    float o0 = vx.x * inv * vw.x;
    float o1 = vx.y * inv * vw.y;
    float o2 = vx.z * inv * vw.z;
    float o3 = vx.w * inv * vw.w;
    if (!isfinite(o0)) o0 = 0.0f;
    if (!isfinite(o1)) o1 = 0.0f;
    if (!isfinite(o2)) o2 = 0.0f;
    if (!isfinite(o3)) o3 = 0.0f;
    ushort4 o;
    o.x = f2bf(o0); o.y = f2bf(o1); o.z = f2bf(o2); o.w = f2bf(o3);
    ((ushort4*)(out + (size_t)row * Dm))[tid] = o;
}

// ---------------- per-head RMSNorm over hd=64 (fp32 in-place) ----------------
__global__ __launch_bounds__(64) void rmsnorm_head(float* __restrict__ qk,
                                                   const float* __restrict__ w) {
    int r = blockIdx.x, lane = threadIdx.x;
    size_t idx = (size_t)r * HDm + lane;
    float xv = clamp10k(qk[idx]);
    float ss = xv * xv;
#pragma unroll
    for (int off = 32; off >= 1; off >>= 1) ss += __shfl_xor(ss, off, 64);
    float mean = ss * (1.0f / HDm);
    float inv = 1.0f / sqrtf(fmaxf(mean, EPSf) + EPSf);
    float o = xv * inv * w[lane];
    qk[idx] = isfinite(o) ? o : 0.0f;
}

// ---------------- weight fp32 -> bf16 with zero padding to Np x Kp ----------------
__global__ __launch_bounds__(256) void convert_w(const float* __restrict__ src,
                                                 ushort* __restrict__ dst,
                                                 int N, int K, int Kp) {
    int n = blockIdx.y;
    int k = blockIdx.x * 256 + threadIdx.x;
    if (k >= Kp) return;
    float v = 0.0f;
    if (n < N && k < K) v = src[(size_t)n * K + k];
    dst[(size_t)n * Kp + k] = f2bf(v);
}

// ---------------- bf16 MFMA GEMM: C(2048 x N) = A(2048 x K) @ Wb(Npad x K)^T + bias ---
// K = padded K (mult of 32); tile 128x128, 4 waves each 64x64 of 16x16x32 MFMAs.
__global__ __launch_bounds__(256) void gemm_bf16(const ushort* __restrict__ A,
                                                 const ushort* __restrict__ Wb,
                                                 const float* __restrict__ bias,
                                                 float* __restrict__ C,
                                                 int K, int N, int ldc, int act) {
    __shared__ ushort As[128 * 32];
    __shared__ ushort Bs[128 * 32];
    const int tid = threadIdx.x;
    const int wave = tid >> 6;
    const int lane = tid & 63;
    const int lane15 = lane & 15;
    const int quad = lane >> 4;
    const int rowBlk = blockIdx.y * 128;
    const int colBlk = blockIdx.x * 128;
    const int wm = (wave >> 1) * 64;
    const int wn = (wave & 1) * 64;

    const int srow = lane >> 2;          // 0..15 within 16-row group
    const int scol = (lane & 3) * 8;     // bf16 col offset

    const ushort* aSrc0 = A + (size_t)(rowBlk + wave * 32 + srow) * K + scol;
    const ushort* bSrc0 = Wb + (size_t)(colBlk + wave * 32 + srow) * K + scol;
    ushort* aDst0 = &As[(wave * 32) * 32];
    ushort* aDst1 = &As[(wave * 32 + 16) * 32];
    ushort* bDst0 = &Bs[(wave * 32) * 32];
    ushort* bDst1 = &Bs[(wave * 32 + 16) * 32];

    f32x4 acc[4][4];
#pragma unroll
    for (int i = 0; i < 4; ++i)
#pragma unroll
        for (int j = 0; j < 4; ++j) acc[i][j] = (f32x4){0.f, 0.f, 0.f, 0.f};

    for (int k0 = 0; k0 < K; k0 += 32) {
        __syncthreads();   // previous iteration's reads complete
        gload16(aSrc0 + k0, aDst0);
        gload16(aSrc0 + k0 + (size_t)16 * K, aDst1);
        gload16(bSrc0 + k0, bDst0);
        gload16(bSrc0 + k0 + (size_t)16 * K, bDst1);
        __syncthreads();   // staging complete

        bf16x8 a[4], b[4];
#pragma unroll
        for (int im = 0; im < 4; ++im)
            a[im] = *(const bf16x8*)&As[(wm + im * 16 + lane15) * 32 + quad * 8];
#pragma unroll
        for (int in = 0; in < 4; ++in)
            b[in] = *(const bf16x8*)&Bs[(wn + in * 16 + lane15) * 32 + quad * 8];
#pragma unroll
        for (int im = 0; im < 4; ++im)
#pragma unroll
            for (int in = 0; in < 4; ++in)
                acc[im][in] = __builtin_amdgcn_mfma_f32_16x16x32_bf16(
                    a[im], b[in], acc[im][in], 0, 0, 0);
    }

#pragma unroll
    for (int im = 0; im < 4; ++im) {
        int r0 = rowBlk + wm + im * 16 + quad * 4;
#pragma unroll
        for (int in = 0; in < 4; ++in) {
            int c = colBlk + wn + in * 16 + lane15;
            if (c < N) {
                float bia = bias[c];
#pragma unroll
                for (int reg = 0; reg < 4; ++reg) {
                    float v = acc[im][in][reg] + bia;
                    if (act) v = fminf(fmaxf(v, -50.0f), 50.0f);
                    C[(size_t)(r0 + reg) * ldc + c] = v;
                }
            }
        }
    }
}

// ---------------- sliding-window causal attention (fp32 in, bf16 out) ----------------
__global__ __launch_bounds__(256) void attn_k(const float* __restrict__ q,
                                              const float* __restrict__ k,
                                              const float* __restrict__ v,
                                              ushort* __restrict__ out) {
    int i = blockIdx.x, h = blockIdx.y, tid = threadIdx.x;
    __shared__ float qs[HDm];
    __shared__ float p[256];
    __shared__ float red[256];
    int j0 = i - (Wm - 1);
    if (j0 < 0) j0 = 0;
    int nj = i - j0 + 1;

    const float* qrow = q + (size_t)i * Dm + h * HDm;
    if (tid < HDm) qs[tid] = qrow[tid];
    __syncthreads();

    float s = -INFINITY;
    if (tid < nj) {
        const float* krow = k + (size_t)(j0 + tid) * Dm + h * HDm;
        float acc = 0.0f;
#pragma unroll
        for (int d = 0; d < HDm; ++d) acc += qs[d] * krow[d];
        s = acc * 0.125f;
    }

    red[tid] = s;
    __syncthreads();
    for (int st = 128; st > 0; st >>= 1) {
        if (tid < st) red[tid] = fmaxf(red[tid], red[tid + st]);
        __syncthreads();
    }
    float m = red[0];
    __syncthreads();

    float e = (tid < nj) ? expf(s - m) : 0.0f;
    red[tid] = e;
    __syncthreads();
    for (int st = 128; st > 0; st >>= 1) {
        if (tid < st) red[tid] += red[tid + st];
        __syncthreads();
    }
    float denom = red[0];
    p[tid] = e / denom;
    __syncthreads();

    if (tid < HDm) {
        float acc = 0.0f;
        const float* vbase = v + (size_t)j0 * Dm + h * HDm + tid;
        for (int t = 0; t < nj; ++t) acc += p[t] * vbase[(size_t)t * Dm];
        if (!isfinite(acc)) acc = 0.0f;
        out[(size_t)i * Dm + h * HDm + tid] = f2bf(acc);
    }
}

// ---------------- elementwise: x += t ----------------
__global__ __launch_bounds__(256) void add_k(float* __restrict__ x,
                                             const float* __restrict__ t, int n4) {
    int i = blockIdx.x * 256 + threadIdx.x;
    if (i < n4) {
        float4 a = ((const float4*)x)[i];
        float4 b = ((const float4*)t)[i];
        a.x += b.x; a.y += b.y; a.z += b.z; a.w += b.w;
        ((float4*)x)[i] = a;
    }
}

// ---------------- swiglu: z1b(2048 x 3296 bf16) = silu(z1)*z3, zero-padded ----------
__global__ __launch_bounds__(256) void swiglu_k(const float* __restrict__ z1,
                                                const float* __restrict__ z3,
                                                ushort* __restrict__ z1b) {
    int row = blockIdx.x, tid = threadIdx.x;
    const float* a = z1 + (size_t)row * Im;
    const float* b = z3 + (size_t)row * Im;
    ushort* o = z1b + (size_t)row * 3296;
    for (int c = tid; c < 3296; c += 256) {
        float v = 0.0f;
        if (c < Im) {
            float x = a[c];
            v = x / (1.0f + expf(-x)) * b[c];
        }
        o[c] = f2bf(v);
    }
}

extern "C" void kernel_launch(void* const* d_in, const int* in_sizes, int n_in,
                              void* d_out, int out_size, void* d_ws, size_t ws_size,
                              hipStream_t stream) {
    const int*   tokens  = (const int*)  d_in[0];
    const float* embed_w = (const float*)d_in[1];
    const float* ln1_w   = (const float*)d_in[2];
    const float* ln2_w   = (const float*)d_in[3];
    const float* wq_w    = (const float*)d_in[4];
    const float* wq_b    = (const float*)d_in[5];
    const float* wk_w    = (const float*)d_in[6];
    const float* wk_b    = (const float*)d_in[7];
    const float* wv_w    = (const float*)d_in[8];
    const float* wv_b    = (const float*)d_in[9];
    const float* wo_w    = (const float*)d_in[10];
    const float* wo_b    = (const float*)d_in[11];
    const float* qn_w    = (const float*)d_in[12];
    const float* kn_w    = (const float*)d_in[13];
    const float* w1_w    = (const float*)d_in[14];
    const float* w1_b    = (const float*)d_in[15];
    const float* w2_w    = (const float*)d_in[16];
    const float* w2_b    = (const float*)d_in[17];
    const float* w3_w    = (const float*)d_in[18];
    const float* w3_b    = (const float*)d_in[19];
    const float* lnf_w   = (const float*)d_in[20];
    const float* lm_w    = (const float*)d_in[21];
    const float* lm_b    = (const float*)d_in[22];
    float* out = (float*)d_out;

    const size_t MB = 1ull << 20;
    char* base = (char*)d_ws;
    float*  x    = (float*)(base);             // 8 MB residual
    ushort* xn   = (ushort*)(base + 8 * MB);   // 4 MB normed bf16
    float*  t2   = (float*)(base + 12 * MB);   // 8 MB
    float*  qb   = (float*)(base + 20 * MB);   // 8 MB   } lifetime: attn
    float*  kb   = (float*)(base + 28 * MB);   // 8 MB   }
    float*  vb   = (float*)(base + 36 * MB);   // 8 MB   }
    ushort* attb = (ushort*)(base + 44 * MB);  // 4 MB   }
    float*  z1   = (float*)(base + 20 * MB);   // 26.9 MB, reuses qb..attb
    float*  z3   = (float*)(base + 48 * MB);   // 26.9 MB
    ushort* z1b  = (ushort*)(base + 75 * MB);  // 13.5 MB (stride 3296, padded)
    ushort* wbuf = (ushort*)(base + 89 * MB);  // 16.5 MB weight scratch

    const size_t LD = (size_t)Lm * Dm;
    int nLD4 = (int)(LD / 4);

    dim3 gemmD(8, 16);    // N=1024
    dim3 gemmI(26, 16);   // N=3280 (Np=3328)
    dim3 gemmC(63, 16);   // N=8000 (Np=8064) LM chunk

    embed_k<<<Lm, 256, 0, stream>>>(tokens, embed_w, x);

    for (int l = 0; l < NLAYER; ++l) {
        size_t oDD = (size_t)l * Dm * Dm, oD = (size_t)l * Dm;
        size_t oID = (size_t)l * Im * Dm, oI = (size_t)l * Im;
        size_t oH = (size_t)l * HDm;

        rmsnorm_row<<<Lm, 256, 0, stream>>>(x, ln1_w + oD, xn);

        convert_w<<<dim3(4, 1024), 256, 0, stream>>>(wq_w + oDD, wbuf, Dm, Dm, Dm);
        gemm_bf16<<<gemmD, 256, 0, stream>>>(xn, wbuf, wq_b + oD, qb, Dm, Dm, Dm, 0);
        convert_w<<<dim3(4, 1024), 256, 0, stream>>>(wk_w + oDD, wbuf, Dm, Dm, Dm);
        gemm_bf16<<<gemmD, 256, 0, stream>>>(xn, wbuf, wk_b + oD, kb, Dm, Dm, Dm, 0);
        convert_w<<<dim3(4, 1024), 256, 0, stream>>>(wv_w + oDD, wbuf, Dm, Dm, Dm);
        gemm_bf16<<<gemmD, 256, 0, stream>>>(xn, wbuf, wv_b + oD, vb, Dm, Dm, Dm, 0);

        rmsnorm_head<<<Lm * Hn, 64, 0, stream>>>(qb, qn_w + oH);
        rmsnorm_head<<<Lm * Hn, 64, 0, stream>>>(kb, kn_w + oH);
        attn_k<<<dim3(Lm, Hn), 256, 0, stream>>>(qb, kb, vb, attb);

        convert_w<<<dim3(4, 1024), 256, 0, stream>>>(wo_w + oDD, wbuf, Dm, Dm, Dm);
        gemm_bf16<<<gemmD, 256, 0, stream>>>(attb, wbuf, wo_b + oD, t2, Dm, Dm, Dm, 0);
        add_k<<<(nLD4 + 255) / 256, 256, 0, stream>>>(x, t2, nLD4);

        rmsnorm_row<<<Lm, 256, 0, stream>>>(x, ln2_w + oD, xn);

        convert_w<<<dim3(4, 3328), 256, 0, stream>>>(w1_w + oID, wbuf, Im, Dm, Dm);
        gemm_bf16<<<gemmI, 256, 0, stream>>>(xn, wbuf, w1_b + oI, z1, Dm, Im, Im, 0);
        convert_w<<<dim3(4, 3328), 256, 0, stream>>>(w3_w + oID, wbuf, Im, Dm, Dm);
        gemm_bf16<<<gemmI, 256, 0, stream>>>(xn, wbuf, w3_b + oI, z3, Dm, Im, Im, 0);
        swiglu_k<<<Lm, 256, 0, stream>>>(z1, z3, z1b);

        convert_w<<<dim3(13, 1024), 256, 0, stream>>>(w2_w + oID, wbuf, Dm, Im, 3296);
        gemm_bf16<<<gemmD, 256, 0, stream>>>(z1b, wbuf, w2_b + oD, t2, 3296, Dm, Dm, 0);
        add_k<<<(nLD4 + 255) / 256, 256, 0, stream>>>(x, t2, nLD4);
    }

    rmsnorm_row<<<Lm, 256, 0, stream>>>(x, lnf_w, xn);
    for (int c = 0; c < 4; ++c) {
        convert_w<<<dim3(4, 8064), 256, 0, stream>>>(lm_w + (size_t)c * 8000 * Dm,
                                                     wbuf, 8000, Dm, Dm);
        gemm_bf16<<<gemmC, 256, 0, stream>>>(xn, wbuf, lm_b + c * 8000,
                                             out + c * 8000, Dm, 8000, Vm, 1);
    }
}